// Round 10
// baseline (96.918 us; speedup 1.0000x reference)
//
#include <hip/hip_runtime.h>

#define IN_DIM   4096
#define OUT_DIM  4096
#define FAN_IN   64
#define ROWS     8
#define NTHREADS 512
#define O_PER_THREAD (OUT_DIM / NTHREADS) // 8
#define MT_BYTES ((size_t)(FAN_IN / 4) * OUT_DIM * 16)  // 1 MB per table

typedef __fp16 v2h __attribute__((ext_vector_type(2)));

// Bijective 16B-block swizzle: spreads LDS bank-start groups.
__device__ __forceinline__ int bswz(int m) {
    return (m & ~7) | ((m ^ (m >> 3)) & 7);
}

// pack two f32 -> two f16 (RTZ) in one v_cvt_pkrtz_f16_f32
__device__ __forceinline__ unsigned int pack_f16(float a, float b) {
    v2h h = __builtin_amdgcn_cvt_pkrtz(a, b);
    unsigned int u;
    __builtin_memcpy(&u, &h, sizeof(u));
    return u;
}

// Pre-transpose M/W with PRE-SWIZZLED mask: Mt[kk][o] = bswz applied already.
__global__ __launch_bounds__(256)
void transpose_mw(const int* __restrict__ M, const float* __restrict__ W,
                  int4* __restrict__ Mt, float4* __restrict__ Wt)
{
    const int t  = blockIdx.x * 256 + threadIdx.x;  // [0, 65536)
    const int kk = t >> 12;                         // 0..15
    const int o  = t & (OUT_DIM - 1);
    int4 m = ((const int4*)(M + (size_t)o * FAN_IN))[kk];
    m.x = bswz(m.x); m.y = bswz(m.y); m.z = bswz(m.z); m.w = bswz(m.w);
    Mt[kk * OUT_DIM + o] = m;
    Wt[kk * OUT_DIM + o] = ((const float4*)(W + (size_t)o * FAN_IN))[kk];
}

// v_fma_mix_f32: acc += (f16 half of pk) * w   (f16->f32 convert is exact, fma in f32)
#define FMAMIX_LO(acc, pk, w)                                                  \
    asm("v_fma_mix_f32 %0, %1, %2, %0 op_sel:[0,0,0] op_sel_hi:[1,0,0]"        \
        : "+v"(acc) : "v"(pk), "v"(w))
#define FMAMIX_HI(acc, pk, w)                                                  \
    asm("v_fma_mix_f32 %0, %1, %2, %0 op_sel:[1,0,0] op_sel_hi:[1,0,0]"        \
        : "+v"(acc) : "v"(pk), "v"(w))

// 64 KiB LDS -> 2 blocks/CU (LDS-capped, 16 waves/CU). VGPR cap 128.
template <bool TRANSPOSED>
__global__ __launch_bounds__(NTHREADS, 4)
void ffi_sparse_kernel(const float* __restrict__ inp,
                       const float* __restrict__ W,
                       const int*   __restrict__ M,
                       const float* __restrict__ bias,
                       const int4*  __restrict__ Mt,
                       const float4* __restrict__ Wt,
                       float* __restrict__ out)
{
    // [col][8 rows] packed f16 pairs: one uint4 (16 B) per column. 64 KiB.
    __shared__ unsigned int lds[IN_DIM * ROWS / 2];

    const int tid = threadIdx.x;
    const int r0  = blockIdx.x * ROWS;

    // ---------------- stage: 8 rows x 4096 cols, f32 -> f16, transpose ----------------
    #pragma unroll
    for (int t = 0; t < (ROWS * IN_DIM / 16) / NTHREADS; ++t) {   // 4 iterations
        const int tile = tid + t * NTHREADS;     // 0..2047
        const int rblk = tile >> 10;             // 0..1
        const int c4   = (tile & 1023) << 2;     // column base
        const float* src = inp + (size_t)(r0 + rblk * 4) * IN_DIM + c4;
        const float4 v0 = *(const float4*)(src);
        const float4 v1 = *(const float4*)(src + IN_DIM);
        const float4 v2 = *(const float4*)(src + 2 * IN_DIM);
        const float4 v3 = *(const float4*)(src + 3 * IN_DIM);

        unsigned int* p;
        p = lds + bswz(c4 + 0) * 4 + rblk * 2;
        *(uint2*)p = make_uint2(pack_f16(v0.x, v1.x), pack_f16(v2.x, v3.x));
        p = lds + bswz(c4 + 1) * 4 + rblk * 2;
        *(uint2*)p = make_uint2(pack_f16(v0.y, v1.y), pack_f16(v2.y, v3.y));
        p = lds + bswz(c4 + 2) * 4 + rblk * 2;
        *(uint2*)p = make_uint2(pack_f16(v0.z, v1.z), pack_f16(v2.z, v3.z));
        p = lds + bswz(c4 + 3) * 4 + rblk * 2;
        *(uint2*)p = make_uint2(pack_f16(v0.w, v1.w), pack_f16(v2.w, v3.w));
    }
    __syncthreads();

    const uint4* __restrict__ ldsq = (const uint4*)lds;

    // 8 x v_fma_mix_f32 per (o,k): zero unpack instructions.
#define CONSUME(d, wv) {                                                       \
        FMAMIX_LO(acc0, d.x, wv);  FMAMIX_HI(acc1, d.x, wv);                   \
        FMAMIX_LO(acc2, d.y, wv);  FMAMIX_HI(acc3, d.y, wv);                   \
        FMAMIX_LO(acc4, d.z, wv);  FMAMIX_HI(acc5, d.z, wv);                   \
        FMAMIX_LO(acc6, d.w, wv);  FMAMIX_HI(acc7, d.w, wv);                   \
    }

    // Cyclic output mapping -> coalesced stores and coalesced Mt/Wt loads.
    #pragma unroll 1
    for (int i = 0; i < O_PER_THREAD; ++i) {
        const int o = tid + i * NTHREADS;
        const float bv = bias[o];
        float acc0 = bv, acc1 = bv, acc2 = bv, acc3 = bv;
        float acc4 = bv, acc5 = bv, acc6 = bv, acc7 = bv;

        const int4*   mp = (const int4*)(M + (size_t)o * FAN_IN);   // fallback
        const float4* wp = (const float4*)(W + (size_t)o * FAN_IN);

        // 3-stage pipeline over 16 trips of 4 k:
        //   issue ds-reads for trip c+1, prefetch m/w for trip c+3, consume trip c.
        uint4  dbuf[2][4];
        int4   mbuf[4];
        float4 wbuf[4];

#define MW_LOAD(dst_m, dst_w, c_) {                                            \
        if (TRANSPOSED) {                                                      \
            dst_m = Mt[(c_) * OUT_DIM + o];    /* pre-swizzled, contiguous */  \
            dst_w = Wt[(c_) * OUT_DIM + o];                                    \
        } else {                                                               \
            int4 mr = mp[(c_)];                                                \
            mr.x = bswz(mr.x); mr.y = bswz(mr.y);                              \
            mr.z = bswz(mr.z); mr.w = bswz(mr.w);                              \
            dst_m = mr;                                                        \
            dst_w = wp[(c_)];                                                  \
        }                                                                      \
    }

        MW_LOAD(mbuf[0], wbuf[0], 0);
        MW_LOAD(mbuf[1], wbuf[1], 1);
        MW_LOAD(mbuf[2], wbuf[2], 2);

        {   // issue trip 0
            const int4 m = mbuf[0];
            dbuf[0][0] = ldsq[m.x];
            dbuf[0][1] = ldsq[m.y];
            dbuf[0][2] = ldsq[m.z];
            dbuf[0][3] = ldsq[m.w];
        }

        #pragma unroll
        for (int c = 0; c < FAN_IN / 4; ++c) {        // 16 bodies, fully unrolled
            if (c + 1 < FAN_IN / 4) {                 // issue trip c+1
                const int4 m = mbuf[(c + 1) & 3];
                dbuf[(c + 1) & 1][0] = ldsq[m.x];
                dbuf[(c + 1) & 1][1] = ldsq[m.y];
                dbuf[(c + 1) & 1][2] = ldsq[m.z];
                dbuf[(c + 1) & 1][3] = ldsq[m.w];
            }
            if (c + 3 < FAN_IN / 4) {                 // prefetch m/w trip c+3
                MW_LOAD(mbuf[(c + 3) & 3], wbuf[(c + 3) & 3], c + 3);
            }
            const float4 w = wbuf[c & 3];             // consume trip c
            CONSUME(dbuf[c & 1][0], w.x);
            CONSUME(dbuf[c & 1][1], w.y);
            CONSUME(dbuf[c & 1][2], w.z);
            CONSUME(dbuf[c & 1][3], w.w);
        }
#undef MW_LOAD

        float* op = out + (size_t)r0 * OUT_DIM + o;
        op[0 * OUT_DIM] = acc0;
        op[1 * OUT_DIM] = acc1;
        op[2 * OUT_DIM] = acc2;
        op[3 * OUT_DIM] = acc3;
        op[4 * OUT_DIM] = acc4;
        op[5 * OUT_DIM] = acc5;
        op[6 * OUT_DIM] = acc6;
        op[7 * OUT_DIM] = acc7;
    }
#undef CONSUME
}

extern "C" void kernel_launch(void* const* d_in, const int* in_sizes, int n_in,
                              void* d_out, int out_size, void* d_ws, size_t ws_size,
                              hipStream_t stream) {
    const float* inp  = (const float*)d_in[0];
    const float* W    = (const float*)d_in[1];
    const int*   M    = (const int*)d_in[2];
    const float* bias = (const float*)d_in[3];
    float* out = (float*)d_out;

    const int n_rows = in_sizes[0] / IN_DIM;          // 4096
    dim3 grid(n_rows / ROWS), block(NTHREADS);

    const bool use_t = ws_size >= 2 * MT_BYTES;
    if (use_t) {
        int4*   Mt = (int4*)d_ws;
        float4* Wt = (float4*)((char*)d_ws + MT_BYTES);
        transpose_mw<<<dim3(OUT_DIM * (FAN_IN / 4) / 256), dim3(256), 0, stream>>>(M, W, Mt, Wt);
        ffi_sparse_kernel<true><<<grid, block, 0, stream>>>(inp, W, M, bias, Mt, Wt, out);
    } else {
        ffi_sparse_kernel<false><<<grid, block, 0, stream>>>(inp, W, M, bias,
                                                             (const int4*)nullptr,
                                                             (const float4*)nullptr, out);
    }
}

// Round 11
// 74.547 us; speedup vs baseline: 1.3001x; 1.3001x over previous
//
#include <hip/hip_runtime.h>

#define IN_DIM   4096
#define OUT_DIM  4096
#define FAN_IN   64
#define ROWS     8
#define NTHREADS 512
#define O_PER_THREAD (OUT_DIM / NTHREADS) // 8
#define MT_BYTES ((size_t)(FAN_IN / 4) * OUT_DIM * 16)  // 1 MB per table

typedef __fp16 v2h __attribute__((ext_vector_type(2)));

// Bijective 16B-block swizzle: spreads LDS bank-start groups.
__device__ __forceinline__ int bswz(int m) {
    return (m & ~7) | ((m ^ (m >> 3)) & 7);
}

// pack two f32 -> two f16 (RTZ) in one v_cvt_pkrtz_f16_f32
__device__ __forceinline__ unsigned int pack_f16(float a, float b) {
    v2h h = __builtin_amdgcn_cvt_pkrtz(a, b);
    unsigned int u;
    __builtin_memcpy(&u, &h, sizeof(u));
    return u;
}

// Pre-transpose M/W. Mt stores PRE-SWIZZLED BYTE offsets (bswz(m)*16), so the
// hot loop's LDS gather is a bare char*+off read: zero address math.
__global__ __launch_bounds__(256)
void transpose_mw(const int* __restrict__ M, const float* __restrict__ W,
                  int4* __restrict__ Mt, float4* __restrict__ Wt)
{
    const int t  = blockIdx.x * 256 + threadIdx.x;  // [0, 65536)
    const int kk = t >> 12;                         // 0..15
    const int o  = t & (OUT_DIM - 1);
    int4 m = ((const int4*)(M + (size_t)o * FAN_IN))[kk];
    m.x = bswz(m.x) << 4; m.y = bswz(m.y) << 4;
    m.z = bswz(m.z) << 4; m.w = bswz(m.w) << 4;
    Mt[kk * OUT_DIM + o] = m;
    Wt[kk * OUT_DIM + o] = ((const float4*)(W + (size_t)o * FAN_IN))[kk];
}

// v_fma_mix_f32: acc += (f16 half of pk) * w   (f16->f32 convert exact, fma in f32)
#define FMAMIX_LO(acc, pk, w)                                                  \
    asm("v_fma_mix_f32 %0, %1, %2, %0 op_sel:[0,0,0] op_sel_hi:[1,0,0]"        \
        : "+v"(acc) : "v"(pk), "v"(w))
#define FMAMIX_HI(acc, pk, w)                                                  \
    asm("v_fma_mix_f32 %0, %1, %2, %0 op_sel:[1,0,0] op_sel_hi:[1,0,0]"        \
        : "+v"(acc) : "v"(pk), "v"(w))

// 64 KiB LDS -> 2 blocks/CU (LDS-capped, 16 waves/CU). VGPR cap 128.
template <bool TRANSPOSED>
__global__ __launch_bounds__(NTHREADS, 4)
void ffi_sparse_kernel(const float* __restrict__ inp,
                       const float* __restrict__ W,
                       const int*   __restrict__ M,
                       const float* __restrict__ bias,
                       const int4*  __restrict__ Mt,
                       const float4* __restrict__ Wt,
                       float* __restrict__ out)
{
    // [col][8 rows] packed f16 pairs: one uint4 (16 B) per column. 64 KiB.
    __shared__ unsigned int lds[IN_DIM * ROWS / 2];

    const int tid = threadIdx.x;
    const int r0  = blockIdx.x * ROWS;

    // ---------------- stage: 8 rows x 4096 cols, f32 -> f16, transpose ----------------
    #pragma unroll
    for (int t = 0; t < (ROWS * IN_DIM / 16) / NTHREADS; ++t) {   // 4 iterations
        const int tile = tid + t * NTHREADS;     // 0..2047
        const int rblk = tile >> 10;             // 0..1
        const int c4   = (tile & 1023) << 2;     // column base
        const float* src = inp + (size_t)(r0 + rblk * 4) * IN_DIM + c4;
        const float4 v0 = *(const float4*)(src);
        const float4 v1 = *(const float4*)(src + IN_DIM);
        const float4 v2 = *(const float4*)(src + 2 * IN_DIM);
        const float4 v3 = *(const float4*)(src + 3 * IN_DIM);

        unsigned int* p;
        p = lds + bswz(c4 + 0) * 4 + rblk * 2;
        *(uint2*)p = make_uint2(pack_f16(v0.x, v1.x), pack_f16(v2.x, v3.x));
        p = lds + bswz(c4 + 1) * 4 + rblk * 2;
        *(uint2*)p = make_uint2(pack_f16(v0.y, v1.y), pack_f16(v2.y, v3.y));
        p = lds + bswz(c4 + 2) * 4 + rblk * 2;
        *(uint2*)p = make_uint2(pack_f16(v0.z, v1.z), pack_f16(v2.z, v3.z));
        p = lds + bswz(c4 + 3) * 4 + rblk * 2;
        *(uint2*)p = make_uint2(pack_f16(v0.w, v1.w), pack_f16(v2.w, v3.w));
    }
    __syncthreads();

    const char* __restrict__ ldsb = (const char*)lds;

#define LDQ(off) (*(const uint4*)(ldsb + (off)))

    // 8 x v_fma_mix_f32 per (o,k): zero unpack instructions.
#define CONSUME(d, wv) {                                                       \
        FMAMIX_LO(acc0, d.x, wv);  FMAMIX_HI(acc1, d.x, wv);                   \
        FMAMIX_LO(acc2, d.y, wv);  FMAMIX_HI(acc3, d.y, wv);                   \
        FMAMIX_LO(acc4, d.z, wv);  FMAMIX_HI(acc5, d.z, wv);                   \
        FMAMIX_LO(acc6, d.w, wv);  FMAMIX_HI(acc7, d.w, wv);                   \
    }
#define ISSUE4(D0,D1,D2,D3, MN) {                                              \
        D0 = LDQ(MN.x); D1 = LDQ(MN.y); D2 = LDQ(MN.z); D3 = LDQ(MN.w); }
#define CONS4(D0,D1,D2,D3, WC) {                                               \
        CONSUME(D0, WC.x); CONSUME(D1, WC.y);                                  \
        CONSUME(D2, WC.z); CONSUME(D3, WC.w); }
#define MWLD(dm, dw, idx) {                                                    \
        if (TRANSPOSED) {                                                      \
            dm = Mt[(idx) * OUT_DIM + o];                                      \
            dw = Wt[(idx) * OUT_DIM + o];                                      \
        } else {                                                               \
            int4 mr = mp[(idx)];                                               \
            mr.x = bswz(mr.x) << 4; mr.y = bswz(mr.y) << 4;                    \
            mr.z = bswz(mr.z) << 4; mr.w = bswz(mr.w) << 4;                    \
            dm = mr; dw = wp[(idx)];                                           \
        } }

    // Cyclic output mapping -> coalesced stores and coalesced Mt/Wt loads.
    #pragma unroll 1
    for (int i = 0; i < O_PER_THREAD; ++i) {
        const int o = tid + i * NTHREADS;
        const float bv = bias[o];
        float acc0 = bv, acc1 = bv, acc2 = bv, acc3 = bv;
        float acc4 = bv, acc5 = bv, acc6 = bv, acc7 = bv;

        const int4*   mp = (const int4*)(M + (size_t)o * FAN_IN);   // fallback
        const float4* wp = (const float4*)(W + (size_t)o * FAN_IN);

        // Straight-line 3-stage pipeline, named registers only (no arrays ->
        // no possible scratch). Trip c: issue ds-reads for c+1, prefetch
        // Mt/Wt[c+3], consume c. Buffers alternate dA/dB; m/w are a 4-ring.
        int4   m0, m1, m2, m3;
        float4 w0, w1, w2, w3;
        uint4  dA0, dA1, dA2, dA3, dB0, dB1, dB2, dB3;

        MWLD(m0, w0, 0);  MWLD(m1, w1, 1);  MWLD(m2, w2, 2);
        ISSUE4(dA0,dA1,dA2,dA3, m0);                                   // trip 0 data

        ISSUE4(dB0,dB1,dB2,dB3, m1);  MWLD(m3,w3, 3);   CONS4(dA0,dA1,dA2,dA3, w0);  // c=0
        ISSUE4(dA0,dA1,dA2,dA3, m2);  MWLD(m0,w0, 4);   CONS4(dB0,dB1,dB2,dB3, w1);  // c=1
        ISSUE4(dB0,dB1,dB2,dB3, m3);  MWLD(m1,w1, 5);   CONS4(dA0,dA1,dA2,dA3, w2);  // c=2
        ISSUE4(dA0,dA1,dA2,dA3, m0);  MWLD(m2,w2, 6);   CONS4(dB0,dB1,dB2,dB3, w3);  // c=3
        ISSUE4(dB0,dB1,dB2,dB3, m1);  MWLD(m3,w3, 7);   CONS4(dA0,dA1,dA2,dA3, w0);  // c=4
        ISSUE4(dA0,dA1,dA2,dA3, m2);  MWLD(m0,w0, 8);   CONS4(dB0,dB1,dB2,dB3, w1);  // c=5
        ISSUE4(dB0,dB1,dB2,dB3, m3);  MWLD(m1,w1, 9);   CONS4(dA0,dA1,dA2,dA3, w2);  // c=6
        ISSUE4(dA0,dA1,dA2,dA3, m0);  MWLD(m2,w2,10);   CONS4(dB0,dB1,dB2,dB3, w3);  // c=7
        ISSUE4(dB0,dB1,dB2,dB3, m1);  MWLD(m3,w3,11);   CONS4(dA0,dA1,dA2,dA3, w0);  // c=8
        ISSUE4(dA0,dA1,dA2,dA3, m2);  MWLD(m0,w0,12);   CONS4(dB0,dB1,dB2,dB3, w1);  // c=9
        ISSUE4(dB0,dB1,dB2,dB3, m3);  MWLD(m1,w1,13);   CONS4(dA0,dA1,dA2,dA3, w2);  // c=10
        ISSUE4(dA0,dA1,dA2,dA3, m0);  MWLD(m2,w2,14);   CONS4(dB0,dB1,dB2,dB3, w3);  // c=11
        ISSUE4(dB0,dB1,dB2,dB3, m1);  MWLD(m3,w3,15);   CONS4(dA0,dA1,dA2,dA3, w0);  // c=12
        ISSUE4(dA0,dA1,dA2,dA3, m2);                    CONS4(dB0,dB1,dB2,dB3, w1);  // c=13
        ISSUE4(dB0,dB1,dB2,dB3, m3);                    CONS4(dA0,dA1,dA2,dA3, w2);  // c=14
                                                        CONS4(dB0,dB1,dB2,dB3, w3);  // c=15

        float* op = out + (size_t)r0 * OUT_DIM + o;
        op[0 * OUT_DIM] = acc0;
        op[1 * OUT_DIM] = acc1;
        op[2 * OUT_DIM] = acc2;
        op[3 * OUT_DIM] = acc3;
        op[4 * OUT_DIM] = acc4;
        op[5 * OUT_DIM] = acc5;
        op[6 * OUT_DIM] = acc6;
        op[7 * OUT_DIM] = acc7;
    }
#undef CONSUME
#undef ISSUE4
#undef CONS4
#undef MWLD
#undef LDQ
}

extern "C" void kernel_launch(void* const* d_in, const int* in_sizes, int n_in,
                              void* d_out, int out_size, void* d_ws, size_t ws_size,
                              hipStream_t stream) {
    const float* inp  = (const float*)d_in[0];
    const float* W    = (const float*)d_in[1];
    const int*   M    = (const int*)d_in[2];
    const float* bias = (const float*)d_in[3];
    float* out = (float*)d_out;

    const int n_rows = in_sizes[0] / IN_DIM;          // 4096
    dim3 grid(n_rows / ROWS), block(NTHREADS);

    const bool use_t = ws_size >= 2 * MT_BYTES;
    if (use_t) {
        int4*   Mt = (int4*)d_ws;
        float4* Wt = (float4*)((char*)d_ws + MT_BYTES);
        transpose_mw<<<dim3(OUT_DIM * (FAN_IN / 4) / 256), dim3(256), 0, stream>>>(M, W, Mt, Wt);
        ffi_sparse_kernel<true><<<grid, block, 0, stream>>>(inp, W, M, bias, Mt, Wt, out);
    } else {
        ffi_sparse_kernel<false><<<grid, block, 0, stream>>>(inp, W, M, bias,
                                                             (const int4*)nullptr,
                                                             (const float4*)nullptr, out);
    }
}